// Round 2
// baseline (439.359 us; speedup 1.0000x reference)
//
#include <hip/hip_runtime.h>
#include <hip/hip_bf16.h>

#define BB 16
#define TT 8192
#define HH 256
#define KK 128
#define HQ 64

#define PTILE 128   // tokens per pooling tile
#define NCH 32      // slots per register chunk

// ---------------------------------------------------------------------------
// Phase 1: scores[b,t] = tanh(proj[b,t,:] @ W1 + b1) @ W2 + b2
// 64 tokens per block, proj tile staged in LDS (row stride 260 floats:
// 16B-aligned for float4 reads, odd multiple of 4 -> spread banks).
// Each of 4 waves owns a wave-uniform 16-wide j-slice of W1 fetched via the
// scalar pipe (readfirstlane -> s_load), so the VALU only issues FMAs:
// 64 FMA per ds_read_b128.
// ---------------------------------------------------------------------------
__global__ __launch_bounds__(256, 2) void scores_kernel(
    const float* __restrict__ proj, const float* __restrict__ W1,
    const float* __restrict__ b1, const float* __restrict__ W2,
    const float* __restrict__ b2, float* __restrict__ scores)
{
  __shared__ __align__(16) float pt[64][260];   // 64 tokens x 256 dims
  __shared__ float part[4][64];
  const int tid = threadIdx.x;
  const long long tile = blockIdx.x;            // 64 tokens each
  const float4* src4 = (const float4*)(proj + tile * (64LL * HH));

  #pragma unroll
  for (int r = 0; r < 16; ++r) {
    int f = r * 256 + tid;        // flat float4 index within tile
    int t = f >> 6;
    int c = f & 63;
    *(float4*)&pt[t][4 * c] = src4[f];
  }
  __syncthreads();

  const int lane = tid & 63;
  const int wv = __builtin_amdgcn_readfirstlane(tid >> 6);  // uniform j-slice
  const float* __restrict__ w1p = W1 + wv * 16;             // row stride = 64

  float acc[16];
  #pragma unroll
  for (int r = 0; r < 16; ++r) acc[r] = b1[wv * 16 + r];

  for (int i = 0; i < HH; i += 4) {
    float4 p = *(const float4*)&pt[lane][i];
    const float* __restrict__ r0 = w1p + (i + 0) * 64;
    const float* __restrict__ r1 = w1p + (i + 1) * 64;
    const float* __restrict__ r2 = w1p + (i + 2) * 64;
    const float* __restrict__ r3 = w1p + (i + 3) * 64;
    #pragma unroll
    for (int r = 0; r < 16; ++r) acc[r] = fmaf(p.x, r0[r], acc[r]);
    #pragma unroll
    for (int r = 0; r < 16; ++r) acc[r] = fmaf(p.y, r1[r], acc[r]);
    #pragma unroll
    for (int r = 0; r < 16; ++r) acc[r] = fmaf(p.z, r2[r], acc[r]);
    #pragma unroll
    for (int r = 0; r < 16; ++r) acc[r] = fmaf(p.w, r3[r], acc[r]);
  }

  float sp = 0.f;
  #pragma unroll
  for (int r = 0; r < 16; ++r) sp += tanhf(acc[r]) * W2[wv * 16 + r];
  part[wv][lane] = sp;
  __syncthreads();

  if (tid < 64) {
    float s = part[0][tid] + part[1][tid] + part[2][tid] + part[3][tid] + b2[0];
    scores[tile * 64 + tid] = s;
  }
}

// ---------------------------------------------------------------------------
// Phase 2: per (b,k) slot: m = max score over [start,end), invden = 1/sum(exp).
// invden == 0 encodes "inactive slot" (mask<=0 or empty span).
// ---------------------------------------------------------------------------
__global__ __launch_bounds__(256) void slotstats_kernel(
    const float* __restrict__ scores, const int* __restrict__ boundaries,
    const int* __restrict__ slot_mask, float* __restrict__ m_arr,
    float* __restrict__ invden)
{
  const int slot = blockIdx.x;        // b*K + k
  const int b = slot >> 7;
  const int tid = threadIdx.x;
  const int st = boundaries[slot * 2 + 0];
  const int en = boundaries[slot * 2 + 1];
  const int mk = slot_mask[slot];
  __shared__ float red[4];

  if (mk <= 0 || en <= st) {
    if (tid == 0) { m_arr[slot] = 0.f; invden[slot] = 0.f; }
    return;
  }
  const float* sc = scores + (long long)b * TT;

  float mx = -3.4e38f;
  for (int t = st + tid; t < en; t += 256) mx = fmaxf(mx, sc[t]);
  #pragma unroll
  for (int o = 32; o > 0; o >>= 1) mx = fmaxf(mx, __shfl_xor(mx, o));
  if ((tid & 63) == 0) red[tid >> 6] = mx;
  __syncthreads();
  mx = fmaxf(fmaxf(red[0], red[1]), fmaxf(red[2], red[3]));
  __syncthreads();   // red reused below

  float se = 0.f;
  for (int t = st + tid; t < en; t += 256) se += expf(sc[t] - mx);
  #pragma unroll
  for (int o = 32; o > 0; o >>= 1) se += __shfl_xor(se, o);
  if ((tid & 63) == 0) red[tid >> 6] = se;
  __syncthreads();
  if (tid == 0) {
    float den = red[0] + red[1] + red[2] + red[3];
    m_arr[slot] = mx;
    invden[slot] = 1.f / den;
  }
}

// ---------------------------------------------------------------------------
// Phase 3: out[b,k,h] += sum_{t in tile} w[t,k] * proj[b,t,h]
// Block = one (b, 128-token tile). Build w[slot][token] in LDS, then stream
// proj once (float2 per lane: h = 2*tid, 2*tid+1), 32-slot register
// accumulators (compile-time indexed), finish with atomicAdd per (slot,h).
// ---------------------------------------------------------------------------
__global__ __launch_bounds__(128, 3) void pool_kernel(
    const float* __restrict__ proj, const float* __restrict__ scores,
    const int* __restrict__ boundaries, const float* __restrict__ m_arr,
    const float* __restrict__ invden, float* __restrict__ out)
{
  __shared__ float s_lds[PTILE];
  __shared__ __align__(16) float w_lds[NCH][PTILE];   // 16 KB
  __shared__ int   act_k[KK];
  __shared__ float act_m[KK], act_i[KK];
  __shared__ int   act_s[KK], act_e[KK];
  __shared__ int   nact;

  const int tid = threadIdx.x;          // 0..127
  const int b = blockIdx.y;
  const int t0 = blockIdx.x * PTILE;

  if (tid == 0) nact = 0;
  __syncthreads();

  s_lds[tid] = scores[(long long)b * TT + t0 + tid];
  {
    const int k = tid;                  // KK == 128 == blockDim.x
    const int st = boundaries[(b * KK + k) * 2 + 0];
    const int en = boundaries[(b * KK + k) * 2 + 1];
    const float inv = invden[b * KK + k];
    if (inv > 0.f && st < t0 + PTILE && en > t0) {
      int pos = atomicAdd(&nact, 1);
      act_k[pos] = k;
      act_m[pos] = m_arr[b * KK + k];
      act_i[pos] = inv;
      act_s[pos] = st;
      act_e[pos] = en;
    }
  }
  __syncthreads();
  const int na = nact;
  // lane owns h = 2*tid, 2*tid+1; token t is at pb2[t*128]
  const float2* __restrict__ pb2 =
      (const float2*)(proj + ((long long)b * TT + t0) * HH) + tid;

  for (int c = 0; c < na; c += NCH) {
    // build the 32 x 128 weight tile (zero-padded beyond na)
    for (int it = 0; it < NCH; ++it) {
      float w = 0.f;
      int ss = c + it;
      if (ss < na) {
        int tg = t0 + tid;
        if (tg >= act_s[ss] && tg < act_e[ss])
          w = expf(s_lds[tid] - act_m[ss]) * act_i[ss];
      }
      w_lds[it][tid] = w;
    }
    __syncthreads();

    float a0[NCH], a1[NCH];
    #pragma unroll
    for (int s = 0; s < NCH; ++s) { a0[s] = 0.f; a1[s] = 0.f; }

    for (int t4 = 0; t4 < PTILE; t4 += 4) {
      float2 p0 = pb2[(t4 + 0) * 128];
      float2 p1 = pb2[(t4 + 1) * 128];
      float2 p2 = pb2[(t4 + 2) * 128];
      float2 p3 = pb2[(t4 + 3) * 128];
      #pragma unroll
      for (int s = 0; s < NCH; ++s) {
        float4 wv = *(const float4*)&w_lds[s][t4];   // uniform -> broadcast
        a0[s] = fmaf(wv.x, p0.x, a0[s]);  a1[s] = fmaf(wv.x, p0.y, a1[s]);
        a0[s] = fmaf(wv.y, p1.x, a0[s]);  a1[s] = fmaf(wv.y, p1.y, a1[s]);
        a0[s] = fmaf(wv.z, p2.x, a0[s]);  a1[s] = fmaf(wv.z, p2.y, a1[s]);
        a0[s] = fmaf(wv.w, p3.x, a0[s]);  a1[s] = fmaf(wv.w, p3.y, a1[s]);
      }
    }

    #pragma unroll
    for (int s = 0; s < NCH; ++s) {
      if (c + s < na) {
        float* op = out + ((long long)(b * KK + act_k[c + s])) * HH + 2 * tid;
        atomicAdd(op, a0[s]);
        atomicAdd(op + 1, a1[s]);
      }
    }
    __syncthreads();
  }
}

extern "C" void kernel_launch(void* const* d_in, const int* in_sizes, int n_in,
                              void* d_out, int out_size, void* d_ws, size_t ws_size,
                              hipStream_t stream)
{
  const float* proj       = (const float*)d_in[0];
  const int*   boundaries = (const int*)d_in[1];
  const int*   slot_mask  = (const int*)d_in[2];
  const float* W1         = (const float*)d_in[3];
  const float* b1         = (const float*)d_in[4];
  const float* W2         = (const float*)d_in[5];
  const float* b2         = (const float*)d_in[6];
  float* out = (float*)d_out;

  float* ws     = (float*)d_ws;
  float* scores = ws;                        // B*T floats
  float* m_arr  = ws + (size_t)BB * TT;      // B*K floats
  float* invden = m_arr + BB * KK;           // B*K floats

  hipMemsetAsync(d_out, 0, (size_t)out_size * sizeof(float), stream);

  scores_kernel<<<dim3(BB * TT / 64), dim3(256), 0, stream>>>(
      proj, W1, b1, W2, b2, scores);
  slotstats_kernel<<<dim3(BB * KK), dim3(256), 0, stream>>>(
      scores, boundaries, slot_mask, m_arr, invden);
  pool_kernel<<<dim3(TT / PTILE, BB), dim3(128), 0, stream>>>(
      proj, scores, boundaries, m_arr, invden, out);
}

// Round 3
// 337.348 us; speedup vs baseline: 1.3024x; 1.3024x over previous
//
#include <hip/hip_runtime.h>
#include <hip/hip_bf16.h>

#define BB 16
#define TT 8192
#define HH 256
#define KK 128
#define HQ 64

#define PTILE 128   // tokens per pooling tile
#define NCH 32      // slots per register chunk (covers na~22 in one pass)

typedef __attribute__((ext_vector_type(8))) short short8;
typedef __attribute__((ext_vector_type(4))) float f32x4;

__device__ inline unsigned short bf16_rne(float f) {
  unsigned u = __float_as_uint(f);
  unsigned r = u + 0x7FFF + ((u >> 16) & 1);
  return (unsigned short)(r >> 16);
}
__device__ inline float bf16_to_f(unsigned short h) {
  return __uint_as_float(((unsigned)h) << 16);
}

// ---------------------------------------------------------------------------
// Prep: pack W1 (fp32 [256][64]) into MFMA B-fragment order, bf16 hi + lo.
// Layout: Wp[pass][kstep s][lane l][8 e] with lane l covering col=l&15,
// k = s*32 + (l>>4)*8 + e.  (Same k-map used on the A side -> contraction
// is correct for any internal hw k-permutation.)
// Flat: [s(3b)][n(2b)][l(6b)][e(3b)], n = j-block (wave id).
// ---------------------------------------------------------------------------
__global__ void prep_kernel(const float* __restrict__ W1,
                            unsigned short* __restrict__ Wp)
{
  const int tid = threadIdx.x;
  for (int r = 0; r < 64; ++r) {
    int f = r * 256 + tid;            // 0..16383
    int e = f & 7;
    int l = (f >> 3) & 63;
    int n = (f >> 9) & 3;
    int s = f >> 11;
    int k = s * 32 + ((l >> 4) * 8) + e;
    int j = n * 16 + (l & 15);
    float w = W1[k * HQ + j];
    unsigned short hi = bf16_rne(w);
    unsigned short lo = bf16_rne(w - bf16_to_f(hi));
    Wp[f] = hi;
    Wp[16384 + f] = lo;
  }
}

// ---------------------------------------------------------------------------
// Phase 1 (MFMA): scores[b,t] = tanh(proj[t,:] @ W1 + b1) @ W2 + b2
// Block = 32 tokens, 4 waves; wave w owns j-range [16w,16w+16).
// proj tile staged in LDS as bf16 hi/lo, row padded to 264 ushorts
// (row = 528 B -> uniform 8 words/bank for the b128 fragment reads).
// 3 MFMA passes: hi*hi + hi*lo + lo*hi  (~17-bit effective mantissa).
// ---------------------------------------------------------------------------
__global__ __launch_bounds__(256, 2) void scores_mfma_kernel(
    const float* __restrict__ proj, const unsigned short* __restrict__ Wp,
    const float* __restrict__ b1, const float* __restrict__ W2,
    const float* __restrict__ b2, float* __restrict__ scores)
{
  __shared__ unsigned short Ahi[32][264];
  __shared__ unsigned short Alo[32][264];
  __shared__ float part[4][32];

  const int tid = threadIdx.x;
  const long long tile = blockIdx.x;     // 32 tokens each
  const float4* src4 = (const float4*)(proj + tile * (32LL * HH));

  #pragma unroll
  for (int r = 0; r < 8; ++r) {
    int f = r * 256 + tid;               // float4 index in tile (64 per row)
    int t = f >> 6;
    int c = f & 63;                      // k = 4c
    float4 v = src4[f];
    unsigned short h0 = bf16_rne(v.x), h1 = bf16_rne(v.y);
    unsigned short h2 = bf16_rne(v.z), h3 = bf16_rne(v.w);
    ushort4 hv = make_ushort4(h0, h1, h2, h3);
    ushort4 lv = make_ushort4(bf16_rne(v.x - bf16_to_f(h0)),
                              bf16_rne(v.y - bf16_to_f(h1)),
                              bf16_rne(v.z - bf16_to_f(h2)),
                              bf16_rne(v.w - bf16_to_f(h3)));
    *(ushort4*)&Ahi[t][4 * c] = hv;
    *(ushort4*)&Alo[t][4 * c] = lv;
  }
  __syncthreads();

  const int w = tid >> 6;                // wave id = j-block
  const int l = tid & 63;
  const int g = l >> 4;
  const int c = l & 15;

  f32x4 acc[2];
  #pragma unroll
  for (int m = 0; m < 2; ++m) acc[m] = (f32x4){0.f, 0.f, 0.f, 0.f};

  const short8* wp_hi = (const short8*)Wp;
  const short8* wp_lo = (const short8*)(Wp + 16384);

  #pragma unroll
  for (int s = 0; s < 8; ++s) {
    short8 bhi = wp_hi[(s * 4 + w) * 64 + l];
    short8 blo = wp_lo[(s * 4 + w) * 64 + l];
    #pragma unroll
    for (int m = 0; m < 2; ++m) {
      short8 ahi = *(const short8*)&Ahi[m * 16 + c][s * 32 + g * 8];
      short8 alo = *(const short8*)&Alo[m * 16 + c][s * 32 + g * 8];
      acc[m] = __builtin_amdgcn_mfma_f32_16x16x32_bf16(ahi, bhi, acc[m], 0, 0, 0);
      acc[m] = __builtin_amdgcn_mfma_f32_16x16x32_bf16(ahi, blo, acc[m], 0, 0, 0);
      acc[m] = __builtin_amdgcn_mfma_f32_16x16x32_bf16(alo, bhi, acc[m], 0, 0, 0);
    }
  }

  // Epilogue: h = tanh(acc + b1[j]); partial score = h * W2[j]; sum over j.
  const int j = w * 16 + c;
  const float b1j = b1[j];
  const float w2j = W2[j];

  #pragma unroll
  for (int m = 0; m < 2; ++m) {
    #pragma unroll
    for (int r = 0; r < 4; ++r) {
      float x = tanhf(acc[m][r] + b1j) * w2j;
      x += __shfl_xor(x, 1);
      x += __shfl_xor(x, 2);
      x += __shfl_xor(x, 4);
      x += __shfl_xor(x, 8);             // all 16 lanes of group g now hold sum
      if (c == r) part[w][m * 16 + g * 4 + r] = x;
    }
  }
  __syncthreads();

  if (tid < 32) {
    float s = part[0][tid] + part[1][tid] + part[2][tid] + part[3][tid] + b2[0];
    scores[tile * 32 + tid] = s;
  }
}

// ---------------------------------------------------------------------------
// Phase 2: per (b,k) slot: m = max score over [start,end), invden = 1/sum(exp)
// invden == 0 encodes "inactive slot".
// ---------------------------------------------------------------------------
__global__ __launch_bounds__(256) void slotstats_kernel(
    const float* __restrict__ scores, const int* __restrict__ boundaries,
    const int* __restrict__ slot_mask, float* __restrict__ m_arr,
    float* __restrict__ invden)
{
  const int slot = blockIdx.x;        // b*K + k
  const int b = slot >> 7;
  const int tid = threadIdx.x;
  const int st = boundaries[slot * 2 + 0];
  const int en = boundaries[slot * 2 + 1];
  const int mk = slot_mask[slot];
  __shared__ float red[4];

  if (mk <= 0 || en <= st) {
    if (tid == 0) { m_arr[slot] = 0.f; invden[slot] = 0.f; }
    return;
  }
  const float* sc = scores + (long long)b * TT;

  float mx = -3.4e38f;
  for (int t = st + tid; t < en; t += 256) mx = fmaxf(mx, sc[t]);
  #pragma unroll
  for (int o = 32; o > 0; o >>= 1) mx = fmaxf(mx, __shfl_xor(mx, o));
  if ((tid & 63) == 0) red[tid >> 6] = mx;
  __syncthreads();
  mx = fmaxf(fmaxf(red[0], red[1]), fmaxf(red[2], red[3]));
  __syncthreads();

  float se = 0.f;
  for (int t = st + tid; t < en; t += 256) se += expf(sc[t] - mx);
  #pragma unroll
  for (int o = 32; o > 0; o >>= 1) se += __shfl_xor(se, o);
  if ((tid & 63) == 0) red[tid >> 6] = se;
  __syncthreads();
  if (tid == 0) {
    m_arr[slot] = mx;
    invden[slot] = 1.f / (red[0] + red[1] + red[2] + red[3]);
  }
}

// ---------------------------------------------------------------------------
// Phase 3: out[b,k,h] += sum_{t in tile} w[t,k] * proj[b,t,h]
// Block = (b, 128-token tile), 256 threads, thread owns h = tid.
// 32 slots per chunk -> exactly 32 fp32 register accumulators (compile-time
// indexed), one proj stream for na<=32 (~99% of blocks). Fire-and-forget
// atomicAdd epilogue.
// ---------------------------------------------------------------------------
__global__ __launch_bounds__(256, 4) void pool_kernel(
    const float* __restrict__ proj, const float* __restrict__ scores,
    const int* __restrict__ boundaries, const float* __restrict__ m_arr,
    const float* __restrict__ invden, float* __restrict__ out)
{
  __shared__ float s_lds[PTILE];
  __shared__ __align__(16) float w_lds[NCH][PTILE];   // 16 KB
  __shared__ int   act_k[KK];
  __shared__ float act_m[KK], act_i[KK];
  __shared__ int   act_s[KK], act_e[KK];
  __shared__ int   nact;

  const int tid = threadIdx.x;          // 0..255, h = tid
  const int b = blockIdx.y;
  const int t0 = blockIdx.x * PTILE;

  if (tid == 0) nact = 0;
  __syncthreads();

  if (tid < PTILE) s_lds[tid] = scores[(long long)b * TT + t0 + tid];
  if (tid < KK) {
    const int k = tid;
    const int st = boundaries[(b * KK + k) * 2 + 0];
    const int en = boundaries[(b * KK + k) * 2 + 1];
    const float inv = invden[b * KK + k];
    if (inv > 0.f && st < t0 + PTILE && en > t0) {
      int pos = atomicAdd(&nact, 1);
      act_k[pos] = k;
      act_m[pos] = m_arr[b * KK + k];
      act_i[pos] = inv;
      act_s[pos] = st;
      act_e[pos] = en;
    }
  }
  __syncthreads();
  const int na = nact;
  const float* __restrict__ pb = proj + ((long long)b * TT + t0) * HH + tid;

  for (int c = 0; c < na; c += NCH) {
    // build the 32 x 128 weight tile (zero-padded beyond na): 16 entries/thread
    #pragma unroll
    for (int q = 0; q < 16; ++q) {
      int f = q * 256 + tid;            // 0..4095
      int it = f >> 7;                  // slot within chunk
      int tk = f & 127;                 // token within tile
      float w = 0.f;
      int ss = c + it;
      if (ss < na) {
        int tg = t0 + tk;
        if (tg >= act_s[ss] && tg < act_e[ss])
          w = expf(s_lds[tk] - act_m[ss]) * act_i[ss];
      }
      w_lds[it][tk] = w;
    }
    __syncthreads();

    float a[NCH];
    #pragma unroll
    for (int s = 0; s < NCH; ++s) a[s] = 0.f;

    for (int t4 = 0; t4 < PTILE; t4 += 4) {
      float p0 = pb[(t4 + 0) * HH];
      float p1 = pb[(t4 + 1) * HH];
      float p2 = pb[(t4 + 2) * HH];
      float p3 = pb[(t4 + 3) * HH];
      #pragma unroll
      for (int s = 0; s < NCH; ++s) {
        float4 wv = *(const float4*)&w_lds[s][t4];   // uniform -> broadcast
        a[s] = fmaf(wv.x, p0, a[s]);
        a[s] = fmaf(wv.y, p1, a[s]);
        a[s] = fmaf(wv.z, p2, a[s]);
        a[s] = fmaf(wv.w, p3, a[s]);
      }
    }

    #pragma unroll
    for (int s = 0; s < NCH; ++s) {
      if (c + s < na)
        atomicAdd(out + ((long long)(b * KK + act_k[c + s])) * HH + tid, a[s]);
    }
    __syncthreads();
  }
}

extern "C" void kernel_launch(void* const* d_in, const int* in_sizes, int n_in,
                              void* d_out, int out_size, void* d_ws, size_t ws_size,
                              hipStream_t stream)
{
  const float* proj       = (const float*)d_in[0];
  const int*   boundaries = (const int*)d_in[1];
  const int*   slot_mask  = (const int*)d_in[2];
  const float* W1         = (const float*)d_in[3];
  const float* b1         = (const float*)d_in[4];
  const float* W2         = (const float*)d_in[5];
  const float* b2         = (const float*)d_in[6];
  float* out = (float*)d_out;

  unsigned short* Wp = (unsigned short*)d_ws;          // 2 x 16384 ushorts
  float* scores = (float*)(Wp + 32768);                // B*T floats
  float* m_arr  = scores + (size_t)BB * TT;            // B*K
  float* invden = m_arr + BB * KK;                     // B*K

  hipMemsetAsync(d_out, 0, (size_t)out_size * sizeof(float), stream);

  prep_kernel<<<dim3(1), dim3(256), 0, stream>>>(W1, Wp);
  scores_mfma_kernel<<<dim3(BB * TT / 32), dim3(256), 0, stream>>>(
      proj, Wp, b1, W2, b2, scores);
  slotstats_kernel<<<dim3(BB * KK), dim3(256), 0, stream>>>(
      scores, boundaries, slot_mask, m_arr, invden);
  pool_kernel<<<dim3(TT / PTILE, BB), dim3(256), 0, stream>>>(
      proj, scores, boundaries, m_arr, invden, out);
}

// Round 4
// 312.395 us; speedup vs baseline: 1.4064x; 1.0799x over previous
//
#include <hip/hip_runtime.h>
#include <hip/hip_bf16.h>

#define BB 16
#define TT 8192
#define HH 256
#define KK 128
#define HQ 64

#define PT 64        // tokens per pooling tile

typedef __attribute__((ext_vector_type(8))) short short8;
typedef __attribute__((ext_vector_type(4))) float f32x4;

__device__ inline unsigned short bf16_rne(float f) {
  unsigned u = __float_as_uint(f);
  unsigned r = u + 0x7FFF + ((u >> 16) & 1);
  return (unsigned short)(r >> 16);
}
__device__ inline float bf16_to_f(unsigned short h) {
  return __uint_as_float(((unsigned)h) << 16);
}

// ---------------------------------------------------------------------------
// Prep: pack W1 (fp32 [256][64]) into MFMA B-fragment order, bf16 hi + lo.
// Wp flat: [s(3b)][n(2b)][l(6b)][e(3b)]; k = s*32 + (l>>4)*8 + e, j = n*16+(l&15)
// ---------------------------------------------------------------------------
__global__ void prep_kernel(const float* __restrict__ W1,
                            unsigned short* __restrict__ Wp)
{
  int f = blockIdx.x * 256 + threadIdx.x;   // 0..16383
  int e = f & 7;
  int l = (f >> 3) & 63;
  int n = (f >> 9) & 3;
  int s = f >> 11;
  int k = s * 32 + ((l >> 4) * 8) + e;
  int j = n * 16 + (l & 15);
  float w = W1[k * HQ + j];
  unsigned short hi = bf16_rne(w);
  Wp[f] = hi;
  Wp[16384 + f] = bf16_rne(w - bf16_to_f(hi));
}

// ---------------------------------------------------------------------------
// Phase 1 (MFMA): scores = tanh(proj @ W1 + b1) @ W2 + b2
// 64-token tile, 4 waves; wave w owns j-slice [16w,16w+16). 3-pass hi/lo.
// ---------------------------------------------------------------------------
__global__ __launch_bounds__(256, 2) void scores_mfma_kernel(
    const float* __restrict__ proj, const unsigned short* __restrict__ Wp,
    const float* __restrict__ b1, const float* __restrict__ W2,
    const float* __restrict__ b2, float* __restrict__ scores)
{
  __shared__ unsigned short Ahi[64][264];
  __shared__ unsigned short Alo[64][264];
  __shared__ float part[4][64];

  const int tid = threadIdx.x;
  const long long tile = blockIdx.x;     // 64 tokens each
  const float4* src4 = (const float4*)(proj + tile * (64LL * HH));

  #pragma unroll
  for (int r = 0; r < 16; ++r) {
    int f = r * 256 + tid;               // float4 index in tile (64 per row)
    int t = f >> 6;
    int c = f & 63;                      // k = 4c
    float4 v = src4[f];
    unsigned short h0 = bf16_rne(v.x), h1 = bf16_rne(v.y);
    unsigned short h2 = bf16_rne(v.z), h3 = bf16_rne(v.w);
    *(ushort4*)&Ahi[t][4 * c] = make_ushort4(h0, h1, h2, h3);
    *(ushort4*)&Alo[t][4 * c] = make_ushort4(bf16_rne(v.x - bf16_to_f(h0)),
                                             bf16_rne(v.y - bf16_to_f(h1)),
                                             bf16_rne(v.z - bf16_to_f(h2)),
                                             bf16_rne(v.w - bf16_to_f(h3)));
  }
  __syncthreads();

  const int w = tid >> 6;                // wave id = j-block
  const int l = tid & 63;
  const int g = l >> 4;
  const int c = l & 15;

  f32x4 acc[4];
  #pragma unroll
  for (int m = 0; m < 4; ++m) acc[m] = (f32x4){0.f, 0.f, 0.f, 0.f};

  const short8* wp_hi = (const short8*)Wp;
  const short8* wp_lo = (const short8*)(Wp + 16384);

  #pragma unroll
  for (int s = 0; s < 8; ++s) {
    short8 bhi = wp_hi[(s * 4 + w) * 64 + l];
    short8 blo = wp_lo[(s * 4 + w) * 64 + l];
    #pragma unroll
    for (int m = 0; m < 4; ++m) {
      short8 ahi = *(const short8*)&Ahi[m * 16 + c][s * 32 + g * 8];
      short8 alo = *(const short8*)&Alo[m * 16 + c][s * 32 + g * 8];
      acc[m] = __builtin_amdgcn_mfma_f32_16x16x32_bf16(ahi, bhi, acc[m], 0, 0, 0);
      acc[m] = __builtin_amdgcn_mfma_f32_16x16x32_bf16(ahi, blo, acc[m], 0, 0, 0);
      acc[m] = __builtin_amdgcn_mfma_f32_16x16x32_bf16(alo, bhi, acc[m], 0, 0, 0);
    }
  }

  const int j = w * 16 + c;
  const float b1j = b1[j];
  const float w2j = W2[j];

  #pragma unroll
  for (int m = 0; m < 4; ++m) {
    #pragma unroll
    for (int r = 0; r < 4; ++r) {
      float x = tanhf(acc[m][r] + b1j) * w2j;
      x += __shfl_xor(x, 1);
      x += __shfl_xor(x, 2);
      x += __shfl_xor(x, 4);
      x += __shfl_xor(x, 8);
      if (c == r) part[w][m * 16 + g * 4 + r] = x;
    }
  }
  __syncthreads();

  if (tid < 64) {
    float s = part[0][tid] + part[1][tid] + part[2][tid] + part[3][tid] + b2[0];
    scores[tile * 64 + tid] = s;
  }
}

// ---------------------------------------------------------------------------
// Phase 2: per (b,k) slot: m = max over span, invden = 1/sum(exp); 0 = inactive
// ---------------------------------------------------------------------------
__global__ __launch_bounds__(256) void slotstats_kernel(
    const float* __restrict__ scores, const int* __restrict__ boundaries,
    const int* __restrict__ slot_mask, float* __restrict__ m_arr,
    float* __restrict__ invden)
{
  const int slot = blockIdx.x;        // b*K + k
  const int b = slot >> 7;
  const int tid = threadIdx.x;
  const int st = boundaries[slot * 2 + 0];
  const int en = boundaries[slot * 2 + 1];
  const int mk = slot_mask[slot];
  __shared__ float red[4];

  if (mk <= 0 || en <= st) {
    if (tid == 0) { m_arr[slot] = 0.f; invden[slot] = 0.f; }
    return;
  }
  const float* sc = scores + (long long)b * TT;

  float mx = -3.4e38f;
  for (int t = st + tid; t < en; t += 256) mx = fmaxf(mx, sc[t]);
  #pragma unroll
  for (int o = 32; o > 0; o >>= 1) mx = fmaxf(mx, __shfl_xor(mx, o));
  if ((tid & 63) == 0) red[tid >> 6] = mx;
  __syncthreads();
  mx = fmaxf(fmaxf(red[0], red[1]), fmaxf(red[2], red[3]));
  __syncthreads();

  float se = 0.f;
  for (int t = st + tid; t < en; t += 256) se += expf(sc[t] - mx);
  #pragma unroll
  for (int o = 32; o > 0; o >>= 1) se += __shfl_xor(se, o);
  if ((tid & 63) == 0) red[tid >> 6] = se;
  __syncthreads();
  if (tid == 0) {
    m_arr[slot] = mx;
    invden[slot] = 1.f / (red[0] + red[1] + red[2] + red[3]);
  }
}

// ---------------------------------------------------------------------------
// Phase 3 (MFMA): out[slot][h] += W[32 x 64] * P[64 x 256] per 64-token tile.
// 8 waves x 512 thr; wave owns 32 h (2 n-tiles). A (weights) built in
// registers (lane row = l&15, k = (l>>4)*8+e). B staged transposed in LDS:
// row h = 128 B (64 t x bf16), chunk swizzle c^(h&7) on BOTH write and read
// -> both hit the b128 bank floor. 3-pass hi/lo, fp32 C. Atomic epilogue.
// ---------------------------------------------------------------------------
__global__ __launch_bounds__(512, 4) void pool_mfma_kernel(
    const float* __restrict__ proj, const float* __restrict__ scores,
    const int* __restrict__ boundaries, const float* __restrict__ m_arr,
    const float* __restrict__ invden, float* __restrict__ out)
{
  __shared__ unsigned short Bhi[256 * 64];
  __shared__ unsigned short Blo[256 * 64];
  __shared__ float s_lds[PT];
  __shared__ int   act_k[KK];
  __shared__ float act_m[KK], act_i[KK];
  __shared__ int   act_s[KK], act_e[KK];
  __shared__ int   nact;

  const int tid = threadIdx.x;          // 0..511
  const int b = blockIdx.y;
  const int t0 = blockIdx.x * PT;

  if (tid == 0) nact = 0;
  __syncthreads();

  if (tid < PT) s_lds[tid] = scores[(long long)b * TT + t0 + tid];
  if (tid < KK) {
    const int k = tid;
    const int st = boundaries[(b * KK + k) * 2 + 0];
    const int en = boundaries[(b * KK + k) * 2 + 1];
    const float inv = invden[b * KK + k];
    if (inv > 0.f && st < t0 + PT && en > t0) {
      int pos = atomicAdd(&nact, 1);
      act_k[pos] = k;
      act_m[pos] = m_arr[b * KK + k];
      act_i[pos] = inv;
      act_s[pos] = st;
      act_e[pos] = en;
    }
  }
  __syncthreads();
  const int na = nact;
  if (na == 0) return;                  // uniform exit, no barriers skipped

  // ---- stage B (proj tile, transposed, hi/lo) ----
  {
    const int h = tid & 255;            // column owner
    const int half = tid >> 8;          // 0/1 -> t range 32
    const float* __restrict__ pcol =
        proj + ((long long)b * TT + t0 + half * 32) * HH + h;
    unsigned short* bh = &Bhi[h * 64];
    unsigned short* bl = &Blo[h * 64];
    const int hs = h & 7;
    #pragma unroll
    for (int o = 0; o < 4; ++o) {
      float v[8];
      #pragma unroll
      for (int i = 0; i < 8; ++i) v[i] = pcol[(o * 8 + i) * HH];
      short8 hv, lv;
      #pragma unroll
      for (int i = 0; i < 8; ++i) {
        unsigned short hi = bf16_rne(v[i]);
        hv[i] = (short)hi;
        lv[i] = (short)bf16_rne(v[i] - bf16_to_f(hi));
      }
      int cch = half * 4 + o;
      *(short8*)&bh[(cch ^ hs) << 3] = hv;
      *(short8*)&bl[(cch ^ hs) << 3] = lv;
    }
  }
  __syncthreads();

  const int l = tid & 63;
  const int w = tid >> 6;               // 8 waves
  const int g = l >> 4;
  const int cl = l & 15;
  const int hbase = w * 32;             // wave's 32-h slice

  for (int c0 = 0; c0 < na; c0 += 32) {
    f32x4 acc[2][2];
    #pragma unroll
    for (int m = 0; m < 2; ++m)
      #pragma unroll
      for (int nt = 0; nt < 2; ++nt) acc[m][nt] = (f32x4){0.f, 0.f, 0.f, 0.f};

    #pragma unroll
    for (int ksub = 0; ksub < 2; ++ksub) {
      float4 sv0 = *(const float4*)&s_lds[ksub * 32 + g * 8];
      float4 sv1 = *(const float4*)&s_lds[ksub * 32 + g * 8 + 4];
      float sv[8] = {sv0.x, sv0.y, sv0.z, sv0.w, sv1.x, sv1.y, sv1.z, sv1.w};

      short8 ahi[2], alo[2];
      #pragma unroll
      for (int m = 0; m < 2; ++m) {
        if (c0 + m * 16 < na) {
          int sidx = c0 + m * 16 + cl;
          bool act = sidx < na;
          int ix = act ? sidx : 0;
          float am = act_m[ix], ai = act_i[ix];
          int as = act_s[ix], ae = act_e[ix];
          #pragma unroll
          for (int e = 0; e < 8; ++e) {
            int t = t0 + ksub * 32 + g * 8 + e;
            float wgt = 0.f;
            if (act && t >= as && t < ae) wgt = expf(sv[e] - am) * ai;
            unsigned short hi = bf16_rne(wgt);
            ahi[m][e] = (short)hi;
            alo[m][e] = (short)bf16_rne(wgt - bf16_to_f(hi));
          }
        }
      }

      #pragma unroll
      for (int nt = 0; nt < 2; ++nt) {
        int hr = hbase + nt * 16 + cl;
        int cch = ksub * 4 + g;
        int off = hr * 64 + ((cch ^ (hr & 7)) << 3);
        short8 bhv = *(const short8*)&Bhi[off];
        short8 blv = *(const short8*)&Blo[off];
        #pragma unroll
        for (int m = 0; m < 2; ++m) {
          if (c0 + m * 16 < na) {
            acc[m][nt] = __builtin_amdgcn_mfma_f32_16x16x32_bf16(ahi[m], bhv, acc[m][nt], 0, 0, 0);
            acc[m][nt] = __builtin_amdgcn_mfma_f32_16x16x32_bf16(ahi[m], blv, acc[m][nt], 0, 0, 0);
            acc[m][nt] = __builtin_amdgcn_mfma_f32_16x16x32_bf16(alo[m], bhv, acc[m][nt], 0, 0, 0);
          }
        }
      }
    }

    // epilogue: D row = slot (g*4+r within m-tile), col = h (cl within n-tile)
    #pragma unroll
    for (int m = 0; m < 2; ++m) {
      #pragma unroll
      for (int r = 0; r < 4; ++r) {
        int sc_i = c0 + m * 16 + g * 4 + r;
        if (sc_i < na) {
          long long obase = ((long long)(b * KK + act_k[sc_i])) * HH;
          #pragma unroll
          for (int nt = 0; nt < 2; ++nt)
            atomicAdd(out + obase + hbase + nt * 16 + cl, acc[m][nt][r]);
        }
      }
    }
  }
}

extern "C" void kernel_launch(void* const* d_in, const int* in_sizes, int n_in,
                              void* d_out, int out_size, void* d_ws, size_t ws_size,
                              hipStream_t stream)
{
  const float* proj       = (const float*)d_in[0];
  const int*   boundaries = (const int*)d_in[1];
  const int*   slot_mask  = (const int*)d_in[2];
  const float* W1         = (const float*)d_in[3];
  const float* b1         = (const float*)d_in[4];
  const float* W2         = (const float*)d_in[5];
  const float* b2         = (const float*)d_in[6];
  float* out = (float*)d_out;

  unsigned short* Wp = (unsigned short*)d_ws;          // 2 x 16384 ushorts
  float* scores = (float*)(Wp + 32768);                // B*T floats
  float* m_arr  = scores + (size_t)BB * TT;            // B*K
  float* invden = m_arr + BB * KK;                     // B*K

  hipMemsetAsync(d_out, 0, (size_t)out_size * sizeof(float), stream);

  prep_kernel<<<dim3(64), dim3(256), 0, stream>>>(W1, Wp);
  scores_mfma_kernel<<<dim3(BB * TT / 64), dim3(256), 0, stream>>>(
      proj, Wp, b1, W2, b2, scores);
  slotstats_kernel<<<dim3(BB * KK), dim3(256), 0, stream>>>(
      scores, boundaries, slot_mask, m_arr, invden);
  pool_mfma_kernel<<<dim3(TT / PT, BB), dim3(512), 0, stream>>>(
      proj, scores, boundaries, m_arr, invden, out);
}

// Round 5
// 278.886 us; speedup vs baseline: 1.5754x; 1.1202x over previous
//
#include <hip/hip_runtime.h>
#include <hip/hip_bf16.h>

#define BB 16
#define TT 8192
#define HH 256
#define KK 128
#define HQ 64

#define PT 128       // tokens per pooling tile

typedef __attribute__((ext_vector_type(8))) short short8;
typedef __attribute__((ext_vector_type(4))) float f32x4;

__device__ inline unsigned short bf16_rne(float f) {
  unsigned u = __float_as_uint(f);
  unsigned r = u + 0x7FFF + ((u >> 16) & 1);
  return (unsigned short)(r >> 16);
}
__device__ inline float bf16_to_f(unsigned short h) {
  return __uint_as_float(((unsigned)h) << 16);
}
// cheap split: hi = truncate-to-bf16 (mask), lo = rne(f - hi) packed by pairs
__device__ inline unsigned cvtpk_bf16(float a, float b) {
  union { __hip_bfloat162 h2; unsigned u; } cv;
  cv.h2 = __float22bfloat162_rn(make_float2(a, b));
  return cv.u;
}
__device__ inline float fast_tanh(float x) {
  float t = __expf(-2.f * fabsf(x));
  float r = (1.f - t) / (1.f + t);
  return copysignf(r, x);
}

// ---------------------------------------------------------------------------
// Prep: pack W1 (fp32 [256][64]) into MFMA B-fragment order, bf16 hi + lo.
// Wp flat: [s(3b)][n(2b)][l(6b)][e(3b)]; k = s*32 + (l>>4)*8 + e, j = n*16+(l&15)
// ---------------------------------------------------------------------------
__global__ void prep_kernel(const float* __restrict__ W1,
                            unsigned short* __restrict__ Wp)
{
  int f = blockIdx.x * 256 + threadIdx.x;   // 0..16383
  int e = f & 7;
  int l = (f >> 3) & 63;
  int n = (f >> 9) & 3;
  int s = f >> 11;
  int k = s * 32 + ((l >> 4) * 8) + e;
  int j = n * 16 + (l & 15);
  float w = W1[k * HQ + j];
  unsigned short hi = bf16_rne(w);
  Wp[f] = hi;
  Wp[16384 + f] = bf16_rne(w - bf16_to_f(hi));
}

// ---------------------------------------------------------------------------
// Phase 1 (MFMA): scores = tanh(proj @ W1 + b1) @ W2 + b2
// 64-token tile, 4 waves; wave w owns j-slice [16w,16w+16). 3-pass hi/lo.
// Staging uses trunc-hi (and-mask) + cvt_pk lo: ~4 VALU/elem.
// ---------------------------------------------------------------------------
__global__ __launch_bounds__(256, 2) void scores_mfma_kernel(
    const float* __restrict__ proj, const unsigned short* __restrict__ Wp,
    const float* __restrict__ b1, const float* __restrict__ W2,
    const float* __restrict__ b2, float* __restrict__ scores)
{
  __shared__ unsigned short Ahi[64][264];
  __shared__ unsigned short Alo[64][264];
  __shared__ float part[4][64];

  const int tid = threadIdx.x;
  const long long tile = blockIdx.x;     // 64 tokens each
  const float4* src4 = (const float4*)(proj + tile * (64LL * HH));

  #pragma unroll
  for (int r = 0; r < 16; ++r) {
    int f = r * 256 + tid;               // float4 index in tile (64 per row)
    int t = f >> 6;
    int c = f & 63;                      // k = 4c
    float4 v = src4[f];
    unsigned ux = __float_as_uint(v.x), uy = __float_as_uint(v.y);
    unsigned uz = __float_as_uint(v.z), uw = __float_as_uint(v.w);
    // hi = truncated bf16 (top 16 bits); residual is exact in fp32
    uint2 hi2 = make_uint2((ux >> 16) | (uy & 0xFFFF0000u),
                           (uz >> 16) | (uw & 0xFFFF0000u));
    float lx = v.x - __uint_as_float(ux & 0xFFFF0000u);
    float ly = v.y - __uint_as_float(uy & 0xFFFF0000u);
    float lz = v.z - __uint_as_float(uz & 0xFFFF0000u);
    float lw = v.w - __uint_as_float(uw & 0xFFFF0000u);
    uint2 lo2 = make_uint2(cvtpk_bf16(lx, ly), cvtpk_bf16(lz, lw));
    *(uint2*)&Ahi[t][4 * c] = hi2;
    *(uint2*)&Alo[t][4 * c] = lo2;
  }
  __syncthreads();

  const int w = tid >> 6;                // wave id = j-block
  const int l = tid & 63;
  const int g = l >> 4;
  const int c = l & 15;

  f32x4 acc[4];
  #pragma unroll
  for (int m = 0; m < 4; ++m) acc[m] = (f32x4){0.f, 0.f, 0.f, 0.f};

  const short8* wp_hi = (const short8*)Wp;
  const short8* wp_lo = (const short8*)(Wp + 16384);

  #pragma unroll
  for (int s = 0; s < 8; ++s) {
    short8 bhi = wp_hi[(s * 4 + w) * 64 + l];
    short8 blo = wp_lo[(s * 4 + w) * 64 + l];
    #pragma unroll
    for (int m = 0; m < 4; ++m) {
      short8 ahi = *(const short8*)&Ahi[m * 16 + c][s * 32 + g * 8];
      short8 alo = *(const short8*)&Alo[m * 16 + c][s * 32 + g * 8];
      acc[m] = __builtin_amdgcn_mfma_f32_16x16x32_bf16(ahi, bhi, acc[m], 0, 0, 0);
      acc[m] = __builtin_amdgcn_mfma_f32_16x16x32_bf16(ahi, blo, acc[m], 0, 0, 0);
      acc[m] = __builtin_amdgcn_mfma_f32_16x16x32_bf16(alo, bhi, acc[m], 0, 0, 0);
    }
  }

  const int j = w * 16 + c;
  const float b1j = b1[j];
  const float w2j = W2[j];

  #pragma unroll
  for (int m = 0; m < 4; ++m) {
    #pragma unroll
    for (int r = 0; r < 4; ++r) {
      float x = fast_tanh(acc[m][r] + b1j) * w2j;
      x += __shfl_xor(x, 1);
      x += __shfl_xor(x, 2);
      x += __shfl_xor(x, 4);
      x += __shfl_xor(x, 8);
      if (c == r) part[w][m * 16 + g * 4 + r] = x;
    }
  }
  __syncthreads();

  if (tid < 64) {
    float s = part[0][tid] + part[1][tid] + part[2][tid] + part[3][tid] + b2[0];
    scores[tile * 64 + tid] = s;
  }
}

// ---------------------------------------------------------------------------
// Phase 2: per (b,k) slot: m = max over span, invden = 1/sum(exp); 0 = inactive
// ---------------------------------------------------------------------------
__global__ __launch_bounds__(256) void slotstats_kernel(
    const float* __restrict__ scores, const int* __restrict__ boundaries,
    const int* __restrict__ slot_mask, float* __restrict__ m_arr,
    float* __restrict__ invden)
{
  const int slot = blockIdx.x;        // b*K + k
  const int b = slot >> 7;
  const int tid = threadIdx.x;
  const int st = boundaries[slot * 2 + 0];
  const int en = boundaries[slot * 2 + 1];
  const int mk = slot_mask[slot];
  __shared__ float red[4];

  if (mk <= 0 || en <= st) {
    if (tid == 0) { m_arr[slot] = 0.f; invden[slot] = 0.f; }
    return;
  }
  const float* sc = scores + (long long)b * TT;

  float mx = -3.4e38f;
  for (int t = st + tid; t < en; t += 256) mx = fmaxf(mx, sc[t]);
  #pragma unroll
  for (int o = 32; o > 0; o >>= 1) mx = fmaxf(mx, __shfl_xor(mx, o));
  if ((tid & 63) == 0) red[tid >> 6] = mx;
  __syncthreads();
  mx = fmaxf(fmaxf(red[0], red[1]), fmaxf(red[2], red[3]));
  __syncthreads();

  float se = 0.f;
  for (int t = st + tid; t < en; t += 256) se += __expf(sc[t] - mx);
  #pragma unroll
  for (int o = 32; o > 0; o >>= 1) se += __shfl_xor(se, o);
  if ((tid & 63) == 0) red[tid >> 6] = se;
  __syncthreads();
  if (tid == 0) {
    m_arr[slot] = mx;
    invden[slot] = 1.f / (red[0] + red[1] + red[2] + red[3]);
  }
}

// ---------------------------------------------------------------------------
// Phase 3 (MFMA): out[slot][h] += W[32 x 128] * P[128 x 256] per 128-tok tile.
// 1024 threads = 16 waves, wave owns 16 h. Weight tile built ONCE in LDS
// (32 slots x 16 chunks x {hi,lo} = 1024 builder threads, __expf, no
// redundancy), read back as swizzled ds_read_b128 A-fragments. B (proj)
// staged transposed [h][t] bf16 hi/lo with the same 3-bit chunk swizzle.
// All LDS ops at the 8-word/bank b128 floor. 3-pass hi/lo MFMA, atomic epi.
// ---------------------------------------------------------------------------
__global__ __launch_bounds__(1024, 1) void pool_mfma_kernel(
    const float* __restrict__ proj, const float* __restrict__ scores,
    const int* __restrict__ boundaries, const float* __restrict__ m_arr,
    const float* __restrict__ invden, float* __restrict__ out)
{
  __shared__ unsigned short Bhi[256 * PT];        // 64 KB  [h][t]
  __shared__ unsigned short Blo[256 * PT];        // 64 KB
  __shared__ unsigned short w_lds[2][32][PT];     // 16 KB  [which][slot][t]
  __shared__ float s_lds[PT];
  __shared__ int   act_k[KK];
  __shared__ float act_m[KK], act_i[KK];
  __shared__ int   act_s[KK], act_e[KK];
  __shared__ int   nact;

  const int tid = threadIdx.x;          // 0..1023
  const int b = blockIdx.y;
  const int t0 = blockIdx.x * PT;

  if (tid == 0) nact = 0;
  __syncthreads();

  if (tid < PT) s_lds[tid] = scores[(long long)b * TT + t0 + tid];
  if (tid < KK) {
    const int k = tid;
    const int st = boundaries[(b * KK + k) * 2 + 0];
    const int en = boundaries[(b * KK + k) * 2 + 1];
    const float inv = invden[b * KK + k];
    if (inv > 0.f && st < t0 + PT && en > t0) {
      int pos = atomicAdd(&nact, 1);
      act_k[pos] = k;
      act_m[pos] = m_arr[b * KK + k];
      act_i[pos] = inv;
      act_s[pos] = st;
      act_e[pos] = en;
    }
  }

  // ---- stage B (proj tile, transposed, hi/lo, cheap split) ----
  {
    const int h = tid & 255;            // column owner
    const int q = tid >> 8;             // 0..3 -> 32-token range
    const float* __restrict__ pcol =
        proj + ((long long)b * TT + t0 + q * 32) * HH + h;
    unsigned short* bh = &Bhi[h * PT];
    unsigned short* bl = &Blo[h * PT];
    const int hs = h & 7;
    #pragma unroll
    for (int o = 0; o < 4; ++o) {
      float v[8];
      #pragma unroll
      for (int i = 0; i < 8; ++i) v[i] = pcol[(o * 8 + i) * HH];
      unsigned hiw[4], low[4];
      #pragma unroll
      for (int i = 0; i < 4; ++i) {
        unsigned u0 = __float_as_uint(v[2 * i]);
        unsigned u1 = __float_as_uint(v[2 * i + 1]);
        hiw[i] = (u0 >> 16) | (u1 & 0xFFFF0000u);
        float l0 = v[2 * i] - __uint_as_float(u0 & 0xFFFF0000u);
        float l1 = v[2 * i + 1] - __uint_as_float(u1 & 0xFFFF0000u);
        low[i] = cvtpk_bf16(l0, l1);
      }
      int cch = (q * 4 + o) ^ hs;       // 16 chunks, 3-bit swizzle
      *(uint4*)&bh[cch << 3] = make_uint4(hiw[0], hiw[1], hiw[2], hiw[3]);
      *(uint4*)&bl[cch << 3] = make_uint4(low[0], low[1], low[2], low[3]);
    }
  }
  __syncthreads();
  const int na = nact;
  if (na == 0) return;                  // uniform exit

  const int l = tid & 63;
  const int w = tid >> 6;               // 16 waves, wave owns h slice [16w,16w+16)
  const int g = l >> 4;
  const int cl = l & 15;

  for (int c0 = 0; c0 < na; c0 += 32) {
    // ---- build weight tile in LDS: thread = (which, slot(5b), chunk(4b)) ----
    {
      const int which = tid >> 9;       // 0 = hi, 1 = lo
      const int s5 = (tid >> 4) & 31;   // slot within chunk-of-32
      const int ch = tid & 15;          // 8-token chunk
      const int sg = c0 + s5;
      float wv[8];
      if (sg < na) {
        const float am = act_m[sg], ai = act_i[sg];
        const int as = act_s[sg], ae = act_e[sg];
        #pragma unroll
        for (int e = 0; e < 8; ++e) {
          int t = t0 + ch * 8 + e;
          wv[e] = (t >= as && t < ae) ? __expf(s_lds[ch * 8 + e] - am) * ai : 0.f;
        }
      } else {
        #pragma unroll
        for (int e = 0; e < 8; ++e) wv[e] = 0.f;
      }
      unsigned pk[4];
      if (which == 0) {                 // hi: truncate
        #pragma unroll
        for (int i = 0; i < 4; ++i)
          pk[i] = (__float_as_uint(wv[2 * i]) >> 16) |
                  (__float_as_uint(wv[2 * i + 1]) & 0xFFFF0000u);
      } else {                          // lo: rne of residual
        #pragma unroll
        for (int i = 0; i < 4; ++i) {
          float l0 = wv[2 * i]     - __uint_as_float(__float_as_uint(wv[2 * i])     & 0xFFFF0000u);
          float l1 = wv[2 * i + 1] - __uint_as_float(__float_as_uint(wv[2 * i + 1]) & 0xFFFF0000u);
          pk[i] = cvtpk_bf16(l0, l1);
        }
      }
      int swc = ch ^ (s5 & 7);
      *(uint4*)&w_lds[which][s5][swc << 3] = make_uint4(pk[0], pk[1], pk[2], pk[3]);
    }
    __syncthreads();

    f32x4 acc[2];
    acc[0] = (f32x4){0.f, 0.f, 0.f, 0.f};
    acc[1] = (f32x4){0.f, 0.f, 0.f, 0.f};

    #pragma unroll
    for (int ksub = 0; ksub < 4; ++ksub) {
      // B fragments for this wave's h-slice
      const int hr = w * 16 + cl;
      const int cch = (ksub * 4 + g) ^ (hr & 7);
      short8 bhv = *(const short8*)&Bhi[hr * PT + (cch << 3)];
      short8 blv = *(const short8*)&Blo[hr * PT + (cch << 3)];
      #pragma unroll
      for (int m = 0; m < 2; ++m) {
        if (c0 + m * 16 < na) {
          const int sl = m * 16 + cl;
          const int swc = (ksub * 4 + g) ^ (sl & 7);
          short8 ahi = *(const short8*)&w_lds[0][sl][swc << 3];
          short8 alo = *(const short8*)&w_lds[1][sl][swc << 3];
          acc[m] = __builtin_amdgcn_mfma_f32_16x16x32_bf16(ahi, bhv, acc[m], 0, 0, 0);
          acc[m] = __builtin_amdgcn_mfma_f32_16x16x32_bf16(ahi, blv, acc[m], 0, 0, 0);
          acc[m] = __builtin_amdgcn_mfma_f32_16x16x32_bf16(alo, bhv, acc[m], 0, 0, 0);
        }
      }
    }

    // epilogue: D row = slot (g*4+r within m-tile), col = h (cl of wave slice)
    #pragma unroll
    for (int m = 0; m < 2; ++m) {
      #pragma unroll
      for (int r = 0; r < 4; ++r) {
        int sc_i = c0 + m * 16 + g * 4 + r;
        if (sc_i < na) {
          long long obase = ((long long)(b * KK + act_k[sc_i])) * HH;
          atomicAdd(out + obase + w * 16 + cl, acc[m][r]);
        }
      }
    }
    __syncthreads();
  }
}

extern "C" void kernel_launch(void* const* d_in, const int* in_sizes, int n_in,
                              void* d_out, int out_size, void* d_ws, size_t ws_size,
                              hipStream_t stream)
{
  const float* proj       = (const float*)d_in[0];
  const int*   boundaries = (const int*)d_in[1];
  const int*   slot_mask  = (const int*)d_in[2];
  const float* W1         = (const float*)d_in[3];
  const float* b1         = (const float*)d_in[4];
  const float* W2         = (const float*)d_in[5];
  const float* b2         = (const float*)d_in[6];
  float* out = (float*)d_out;

  unsigned short* Wp = (unsigned short*)d_ws;          // 2 x 16384 ushorts
  float* scores = (float*)(Wp + 32768);                // B*T floats
  float* m_arr  = scores + (size_t)BB * TT;            // B*K
  float* invden = m_arr + BB * KK;                     // B*K

  hipMemsetAsync(d_out, 0, (size_t)out_size * sizeof(float), stream);

  prep_kernel<<<dim3(64), dim3(256), 0, stream>>>(W1, Wp);
  scores_mfma_kernel<<<dim3(BB * TT / 64), dim3(256), 0, stream>>>(
      proj, Wp, b1, W2, b2, scores);
  slotstats_kernel<<<dim3(BB * KK), dim3(256), 0, stream>>>(
      scores, boundaries, slot_mask, m_arr, invden);
  pool_mfma_kernel<<<dim3(TT / PT, BB), dim3(1024), 0, stream>>>(
      proj, scores, boundaries, m_arr, invden, out);
}